// Round 20
// baseline (211.686 us; speedup 1.0000x reference)
//
#include <hip/hip_runtime.h>

typedef float f32x4 __attribute__((ext_vector_type(4)));
typedef short s16x8 __attribute__((ext_vector_type(8)));

#define MOFF 12.0f

__device__ __forceinline__ unsigned short f2bf(float f) {
  unsigned int u = __float_as_uint(f);
  u += 0x7fffu + ((u >> 16) & 1u);
  return (unsigned short)(u >> 16);
}

template <typename T>
__device__ __forceinline__ void gload16(const T* g, T* l) {
  __builtin_amdgcn_global_load_lds(
      (const __attribute__((address_space(1))) void*)g,
      (__attribute__((address_space(3))) void*)l, 16, 0, 0);
}

// ---------------- GroupNorm stats: one block per (b,g) ----------------
__global__ __launch_bounds__(256) void gn_stats_k(const float* __restrict__ x,
                                                  float* __restrict__ meanv,
                                                  float* __restrict__ rstdv) {
  const int bg = blockIdx.x;
  const float4* base = (const float4*)(x + (size_t)bg * 8 * 4096);
  float s = 0.f, q = 0.f;
  for (int i = threadIdx.x; i < 8192; i += 256) {
    float4 v = base[i];
    s += v.x + v.y + v.z + v.w;
    q += v.x * v.x + v.y * v.y + v.z * v.z + v.w * v.w;
  }
  for (int o = 32; o; o >>= 1) { s += __shfl_down(s, o); q += __shfl_down(q, o); }
  __shared__ float ss[4], sq[4];
  const int wv = threadIdx.x >> 6;
  if ((threadIdx.x & 63) == 0) { ss[wv] = s; sq[wv] = q; }
  __syncthreads();
  if (threadIdx.x == 0) {
    s = ss[0] + ss[1] + ss[2] + ss[3];
    q = sq[0] + sq[1] + sq[2] + sq[3];
    float mu = s * (1.f / 32768.f);
    float var = q * (1.f / 32768.f) - mu * mu;
    meanv[bg] = mu;
    rstdv[bg] = rsqrtf(var + 1e-6f);
  }
}

// ------------- GroupNorm apply + transpose: write hT[b][t][c] bf16 -------------
__global__ __launch_bounds__(256) void gn_apply_t_k(const float* __restrict__ x,
    const float* __restrict__ gamma, const float* __restrict__ beta,
    const float* __restrict__ meanv, const float* __restrict__ rstdv,
    unsigned short* __restrict__ hT) {
  __shared__ unsigned short tile[64][72];
  const int b = blockIdx.z, c0 = blockIdx.y * 64, t0 = blockIdx.x * 64;
  const int tid = threadIdx.x;
  {
    const int tr = tid >> 4, tc = (tid & 15) * 4;
    const float* xb = x + ((size_t)b * 256 + c0) * 4096 + t0;
    for (int p2 = 0; p2 < 4; ++p2) {
      int cl = p2 * 16 + tr;
      int c = c0 + cl;
      int bg = b * 32 + (c >> 3);
      float ga = gamma[c] * rstdv[bg];
      float be = beta[c] - meanv[bg] * ga;
      float4 v = *(const float4*)(xb + (size_t)cl * 4096 + tc);
      tile[cl][tc + 0] = f2bf(v.x * ga + be);
      tile[cl][tc + 1] = f2bf(v.y * ga + be);
      tile[cl][tc + 2] = f2bf(v.z * ga + be);
      tile[cl][tc + 3] = f2bf(v.w * ga + be);
    }
  }
  __syncthreads();
  {
    const int orow = tid >> 3, oc = (tid & 7) * 8;
    unsigned short* hb = hT + ((size_t)b * 4096 + t0) * 256 + c0;
    for (int p2 = 0; p2 < 2; ++p2) {
      int tl = p2 * 32 + orow;
      s16x8 w;
#pragma unroll
      for (int j = 0; j < 8; ++j) w[j] = (short)tile[oc + j][tl];
      *(s16x8*)(hb + (size_t)tl * 256 + oc) = w;
    }
  }
}

// ------- 128x64-output MFMA GEMM: 2 m-tiles per block share the staged B -------
enum { EPI_WT = 0, EPI_PB = 1, EPI_FIN = 3, EPI_PBR = 4 };

template <bool AF32, int EPI>
__global__ __launch_bounds__(256) void gemm64x2_k(
    const void* __restrict__ Ap, long long sA, int lda,
    const unsigned short* __restrict__ Bp, long long sB, int ldb,
    void* __restrict__ Op, long long sO, int ldo,
    const float* __restrict__ bias,
    const float* __restrict__ xadd, long long sX,
    float scale, int K) {
  __shared__ s16x8 lsA[2][4][64];
  __shared__ s16x8 lsB[4][64];
  const int tid = threadIdx.x;
  const int m0 = blockIdx.y * 128, n0 = blockIdx.x * 64;
  const int z = blockIdx.z;
  const int lane = tid & 63, wv = tid >> 6;
  const int lrow = lane & 15, lg = lane >> 4;
  const int srow = tid >> 2, scg = tid & 3;
  const int swrow = srow ^ (scg << 1);

  f32x4 acc[2][4];
#pragma unroll
  for (int mt = 0; mt < 2; ++mt)
#pragma unroll
    for (int i = 0; i < 4; ++i) acc[mt][i] = (f32x4){0.f, 0.f, 0.f, 0.f};

  const unsigned short* Bb = Bp + (size_t)z * sB + (size_t)(n0 + srow) * ldb + scg * 8;

  for (int k0 = 0; k0 < K; k0 += 32) {
#pragma unroll
    for (int mt = 0; mt < 2; ++mt) {
      if (AF32) {
        const float* ap = (const float*)Ap + (size_t)z * sA + (size_t)(m0 + mt * 64 + srow) * lda + k0 + scg * 8;
        float4 v0 = *(const float4*)ap;
        float4 v1 = *(const float4*)(ap + 4);
        s16x8 w;
        w[0] = (short)f2bf(v0.x); w[1] = (short)f2bf(v0.y);
        w[2] = (short)f2bf(v0.z); w[3] = (short)f2bf(v0.w);
        w[4] = (short)f2bf(v1.x); w[5] = (short)f2bf(v1.y);
        w[6] = (short)f2bf(v1.z); w[7] = (short)f2bf(v1.w);
        lsA[mt][scg][swrow] = w;
      } else {
        const unsigned short* ap = (const unsigned short*)Ap + (size_t)z * sA + (size_t)(m0 + mt * 64 + srow) * lda + k0 + scg * 8;
        lsA[mt][scg][swrow] = *(const s16x8*)ap;
      }
    }
    lsB[scg][swrow] = *(const s16x8*)(Bb + k0);
    __syncthreads();
    s16x8 af0 = lsA[0][lg][(wv * 16 + lrow) ^ (lg << 1)];
    s16x8 af1 = lsA[1][lg][(wv * 16 + lrow) ^ (lg << 1)];
#pragma unroll
    for (int nt = 0; nt < 4; ++nt) {
      s16x8 bf = lsB[lg][(nt * 16 + lrow) ^ (lg << 1)];
      acc[0][nt] = __builtin_amdgcn_mfma_f32_16x16x32_bf16(af0, bf, acc[0][nt], 0, 0, 0);
      acc[1][nt] = __builtin_amdgcn_mfma_f32_16x16x32_bf16(af1, bf, acc[1][nt], 0, 0, 0);
    }
    __syncthreads();
  }

#pragma unroll
  for (int mt = 0; mt < 2; ++mt) {
    const int mb = m0 + mt * 64 + wv * 16 + lg * 4;
    float bv0 = 0.f, bv1 = 0.f, bv2 = 0.f, bv3 = 0.f;
    if (bias) { bv0 = bias[mb]; bv1 = bias[mb + 1]; bv2 = bias[mb + 2]; bv3 = bias[mb + 3]; }
#pragma unroll
    for (int nt = 0; nt < 4; ++nt) {
      const int n = n0 + nt * 16 + lrow;
      if (EPI == EPI_WT) {
        ushort4 pk;
        pk.x = f2bf((acc[mt][nt][0] + bv0) * scale);
        pk.y = f2bf((acc[mt][nt][1] + bv1) * scale);
        pk.z = f2bf((acc[mt][nt][2] + bv2) * scale);
        pk.w = f2bf((acc[mt][nt][3] + bv3) * scale);
        *(ushort4*)((unsigned short*)Op + (size_t)z * sO + (size_t)n * ldo + mb) = pk;
      } else if (EPI == EPI_PB) {
        unsigned short* o = (unsigned short*)Op + (size_t)z * sO;
        o[(size_t)(mb + 0) * ldo + n] = f2bf(acc[mt][nt][0] + bv0);
        o[(size_t)(mb + 1) * ldo + n] = f2bf(acc[mt][nt][1] + bv1);
        o[(size_t)(mb + 2) * ldo + n] = f2bf(acc[mt][nt][2] + bv2);
        o[(size_t)(mb + 3) * ldo + n] = f2bf(acc[mt][nt][3] + bv3);
      } else if (EPI == EPI_PBR) {
        unsigned short* o = (unsigned short*)Op + (size_t)z * sO;
        const float rc = (xadd + (size_t)z * sX)[n];
        o[(size_t)(mb + 0) * ldo + n] = f2bf((acc[mt][nt][0] + bv0) * rc);
        o[(size_t)(mb + 1) * ldo + n] = f2bf((acc[mt][nt][1] + bv1) * rc);
        o[(size_t)(mb + 2) * ldo + n] = f2bf((acc[mt][nt][2] + bv2) * rc);
        o[(size_t)(mb + 3) * ldo + n] = f2bf((acc[mt][nt][3] + bv3) * rc);
      } else {
        float* o = (float*)Op + (size_t)z * sO;
        const float* xa = xadd + (size_t)z * sX;
        o[(size_t)(mb + 0) * ldo + n] = acc[mt][nt][0] + bv0 + xa[(size_t)(mb + 0) * ldo + n];
        o[(size_t)(mb + 1) * ldo + n] = acc[mt][nt][1] + bv1 + xa[(size_t)(mb + 1) * ldo + n];
        o[(size_t)(mb + 2) * ldo + n] = acc[mt][nt][2] + bv2 + xa[(size_t)(mb + 2) * ldo + n];
        o[(size_t)(mb + 3) * ldo + n] = acc[mt][nt][3] + bv3 + xa[(size_t)(mb + 3) * ldo + n];
      }
    }
  }
}

// ------- pass 1: l[q] = sum_k exp(S - MOFF), fixed offset, no max tracking -------
__global__ __launch_bounds__(256) void attn_stats3_k(
    const unsigned short* __restrict__ qT,
    const unsigned short* __restrict__ kT,
    float* __restrict__ pl) {  // [8][B][T] partial sums
  __shared__ unsigned short kbuf[2][64 * 256];
  const int tid = threadIdx.x;
  const int b = blockIdx.z;
  const int Q0 = blockIdx.x * 256;
  const int kc = blockIdx.y;
  const int lane = tid & 63, wq = tid >> 6;
  const int lrow = lane & 15, lg = lane >> 4;

  const unsigned short* qb = qT + (size_t)b * (4096 * 256);
  const unsigned short* kb = kT + (size_t)b * (4096 * 256);

  s16x8 af[4][8];
#pragma unroll
  for (int mt = 0; mt < 4; ++mt)
#pragma unroll
    for (int ks = 0; ks < 8; ++ks)
      af[mt][ks] = *(const s16x8*)(qb + (size_t)(Q0 + wq * 64 + mt * 16 + lrow) * 256 + ks * 32 + lg * 8);

  float sl[4][4];
#pragma unroll
  for (int mt = 0; mt < 4; ++mt)
#pragma unroll
    for (int j = 0; j < 4; ++j) sl[mt][j] = 0.f;

  int cur = 0;
  {
    const unsigned short* src = kb + (size_t)(kc * 512) * 256;
#pragma unroll
    for (int rep = 0; rep < 8; ++rep) {
      int i = rep * 256 + tid;
      int row = i >> 5, c8 = i & 31;
      gload16(src + (size_t)row * 256 + (c8 ^ (row & 7)) * 8, &kbuf[0][(i - lane) * 8]);
    }
  }
  __syncthreads();

  for (int it = 0; it < 8; ++it) {
    if (it + 1 < 8) {
      const unsigned short* src = kb + (size_t)(kc * 512 + (it + 1) * 64) * 256;
#pragma unroll
      for (int rep = 0; rep < 8; ++rep) {
        int i = rep * 256 + tid;
        int row = i >> 5, c8 = i & 31;
        gload16(src + (size_t)row * 256 + (c8 ^ (row & 7)) * 8, &kbuf[cur ^ 1][(i - lane) * 8]);
      }
    }
#pragma unroll
    for (int nt = 0; nt < 4; ++nt) {
      f32x4 acc[4];
#pragma unroll
      for (int mt = 0; mt < 4; ++mt) acc[mt] = (f32x4){0.f, 0.f, 0.f, 0.f};
#pragma unroll
      for (int ks = 0; ks < 8; ++ks) {
        int row = nt * 16 + lrow;
        int ch = (ks * 4 + lg) ^ (row & 7);
        s16x8 bf = *(const s16x8*)&kbuf[cur][row * 256 + ch * 8];
#pragma unroll
        for (int mt = 0; mt < 4; ++mt)
          acc[mt] = __builtin_amdgcn_mfma_f32_16x16x32_bf16(af[mt][ks], bf, acc[mt], 0, 0, 0);
      }
#pragma unroll
      for (int mt = 0; mt < 4; ++mt)
#pragma unroll
        for (int j = 0; j < 4; ++j) sl[mt][j] += __expf(acc[mt][j] - MOFF);
    }
    __syncthreads();
    cur ^= 1;
  }
#pragma unroll
  for (int mt = 0; mt < 4; ++mt)
#pragma unroll
    for (int j = 0; j < 4; ++j) {
      float v = sl[mt][j];
      v += __shfl_xor(v, 1);
      v += __shfl_xor(v, 2);
      v += __shfl_xor(v, 4);
      v += __shfl_xor(v, 8);
      sl[mt][j] = v;
    }
  if (lrow == 0) {
    float* plb = pl + ((size_t)kc * 4 + b) * 4096;
#pragma unroll
    for (int mt = 0; mt < 4; ++mt)
#pragma unroll
      for (int j = 0; j < 4; ++j)
        plb[Q0 + wq * 64 + mt * 16 + lg * 4 + j] = sl[mt][j];
  }
}

__global__ __launch_bounds__(256) void make_r_k(const float* __restrict__ pl,
                                                float* __restrict__ ra) {
  int i = blockIdx.x * 256 + threadIdx.x;
  int b = i >> 12, q = i & 4095;
  float l = 0.f;
#pragma unroll
  for (int kc = 0; kc < 8; ++kc) l += pl[((size_t)kc * 4 + b) * 4096 + q];
  ra[i] = 1.f / l;
}

// ------- pass 2 v6: fused S-recompute + exp + PV (r pre-folded into v) -------
// grid 256 (1/CU), 512 thr. Block owns k-tile [K0,K0+64) of batch z; q in tiles of 128.
__global__ __launch_bounds__(512) void attn_pv6_k(
    const unsigned short* __restrict__ qT,
    const unsigned short* __restrict__ kT,
    const unsigned short* __restrict__ vt,   // v*r [B][C][T]
    unsigned short* __restrict__ aT) {       // [B][T][C]
  __shared__ unsigned short qbuf[2][128 * 256];  // 64KB x2
  __shared__ unsigned short P[64 * 128];         // 16KB, chunk-XOR swizzled
  const int tid = threadIdx.x;
  const int pidx = blockIdx.x;
  const int z = (pidx >> 1) & 3;                       // batch -> XCD pair
  const int kt = ((pidx >> 3) << 1) | (pidx & 1);      // 0..63
  const int K0 = kt * 64;
  const int lane = tid & 63, w = tid >> 6;
  const int lrow = lane & 15, lg = lane >> 4;
  const int khw = w >> 2;   // k-half (32 rows) this wave computes in S phase
  const int qqw = w & 3;    // q-quarter (32 cols) this wave computes in S phase

  const unsigned short* qg = qT + (size_t)z * (4096 * 256);
  const unsigned short* kg = kT + (size_t)z * (4096 * 256);
  const unsigned short* vg = vt + (size_t)z * (4096 * 256);

  // pinned kf: A-operand rows K0+khw*32 .. +32 (2 tiles x 8 ks)
  s16x8 kf[2][8];
#pragma unroll
  for (int ktl = 0; ktl < 2; ++ktl)
#pragma unroll
    for (int ks = 0; ks < 8; ++ks)
      kf[ktl][ks] = *(const s16x8*)(kg + (size_t)(K0 + khw * 32 + ktl * 16 + lrow) * 256 + ks * 32 + lg * 8);

  f32x4 oacc[2][4];  // out c-tiles (w*32 + ct*16) x k-tiles (nt*16)
#pragma unroll
  for (int ct = 0; ct < 2; ++ct)
#pragma unroll
    for (int nt = 0; nt < 4; ++nt) oacc[ct][nt] = (f32x4){0.f, 0.f, 0.f, 0.f};

  int cur = 0;
  {  // prologue: stage q-tile 0 (128 rows x 512B), pre-swizzled source
#pragma unroll
    for (int rep = 0; rep < 8; ++rep) {
      int i = rep * 512 + tid;
      int row = i >> 5, c8 = i & 31;
      gload16(qg + (size_t)row * 256 + (c8 ^ (row & 7)) * 8, &qbuf[0][(i - lane) * 8]);
    }
  }
  __syncthreads();

  for (int qi = 0; qi < 32; ++qi) {
    const int q0 = qi * 128;
    // v fragments for this iter's PV: global -> reg, in flight through S phase
    s16x8 vf[2][4];
#pragma unroll
    for (int ct = 0; ct < 2; ++ct)
#pragma unroll
      for (int qs = 0; qs < 4; ++qs)
        vf[ct][qs] = *(const s16x8*)(vg + (size_t)(w * 32 + ct * 16 + lrow) * 4096 + q0 + qs * 32 + lg * 8);
    // stage next q-tile
    if (qi + 1 < 32) {
      const unsigned short* src = qg + (size_t)(q0 + 128) * 256;
#pragma unroll
      for (int rep = 0; rep < 8; ++rep) {
        int i = rep * 512 + tid;
        int row = i >> 5, c8 = i & 31;
        gload16(src + (size_t)row * 256 + (c8 ^ (row & 7)) * 8, &qbuf[cur ^ 1][(i - lane) * 8]);
      }
    }
    // S phase: S^T quadrant [khw*32 .. +32][qqw*32 .. +32]
    f32x4 sacc[2][2];
#pragma unroll
    for (int ktl = 0; ktl < 2; ++ktl)
#pragma unroll
      for (int qt = 0; qt < 2; ++qt) sacc[ktl][qt] = (f32x4){0.f, 0.f, 0.f, 0.f};
#pragma unroll
    for (int qt = 0; qt < 2; ++qt) {
#pragma unroll
      for (int ks = 0; ks < 8; ++ks) {
        int row = qqw * 32 + qt * 16 + lrow;
        int ch = (ks * 4 + lg) ^ (row & 7);
        s16x8 qf = *(const s16x8*)&qbuf[cur][row * 256 + ch * 8];
        sacc[0][qt] = __builtin_amdgcn_mfma_f32_16x16x32_bf16(kf[0][ks], qf, sacc[0][qt], 0, 0, 0);
        sacc[1][qt] = __builtin_amdgcn_mfma_f32_16x16x32_bf16(kf[1][ks], qf, sacc[1][qt], 0, 0, 0);
      }
    }
    // exp and write P (bf16), swizzled: elem (k,q) at short index k*128 + ((q>>3)^(k&7))*8 + (q&7)
#pragma unroll
    for (int qt = 0; qt < 2; ++qt) {
      const int ql = qqw * 32 + qt * 16 + lrow;
#pragma unroll
      for (int ktl = 0; ktl < 2; ++ktl)
#pragma unroll
        for (int j = 0; j < 4; ++j) {
          int k = khw * 32 + ktl * 16 + lg * 4 + j;
          float p = __expf(sacc[ktl][qt][j] - MOFF);
          P[k * 128 + (((ql >> 3) ^ (k & 7)) << 3) + (ql & 7)] = f2bf(p);
        }
    }
    __syncthreads();  // P visible; next q-tile staged (vmcnt drained)
    // PV: oacc[c][k] += vtilde[c][q-tile] * P^T[k][q-tile]
#pragma unroll
    for (int qs = 0; qs < 4; ++qs) {
      s16x8 pf[4];
#pragma unroll
      for (int nt = 0; nt < 4; ++nt) {
        int k = nt * 16 + lrow;
        pf[nt] = *(const s16x8*)&P[k * 128 + (((qs * 4 + lg) ^ (k & 7)) << 3)];
      }
#pragma unroll
      for (int ct = 0; ct < 2; ++ct)
#pragma unroll
        for (int nt = 0; nt < 4; ++nt)
          oacc[ct][nt] = __builtin_amdgcn_mfma_f32_16x16x32_bf16(vf[ct][qs], pf[nt], oacc[ct][nt], 0, 0, 0);
    }
    __syncthreads();  // P consumed; safe to overwrite next iter
    cur ^= 1;
  }
  // epilogue: aT[z][K0+k][c]
  unsigned short* ab = aT + (size_t)z * (4096 * 256);
#pragma unroll
  for (int ct = 0; ct < 2; ++ct)
#pragma unroll
    for (int nt = 0; nt < 4; ++nt) {
      int k = K0 + nt * 16 + lrow;
      int c = w * 32 + ct * 16 + lg * 4;
      ushort4 pk;
      pk.x = f2bf(oacc[ct][nt][0]);
      pk.y = f2bf(oacc[ct][nt][1]);
      pk.z = f2bf(oacc[ct][nt][2]);
      pk.w = f2bf(oacc[ct][nt][3]);
      *(ushort4*)(ab + (size_t)k * 256 + c) = pk;
    }
}

extern "C" void kernel_launch(void* const* d_in, const int* in_sizes, int n_in,
                              void* d_out, int out_size, void* d_ws, size_t ws_size,
                              hipStream_t stream) {
  const float* x   = (const float*)d_in[0];
  const float* gns = (const float*)d_in[1];
  const float* gnb = (const float*)d_in[2];
  const float* wq  = (const float*)d_in[3];
  const float* bq  = (const float*)d_in[4];
  const float* wk  = (const float*)d_in[5];
  const float* bk  = (const float*)d_in[6];
  const float* wvp = (const float*)d_in[7];
  const float* bv  = (const float*)d_in[8];
  const float* wo  = (const float*)d_in[9];
  const float* bo  = (const float*)d_in[10];
  float* out = (float*)d_out;

  const int B = 4, C = 256, T = 4096;
  const long long TCe = (long long)T * C;

  char* p = (char*)d_ws;
  unsigned short* hT = (unsigned short*)p; p += (size_t)B * TCe * 2;
  unsigned short* qT = (unsigned short*)p; p += (size_t)B * TCe * 2;
  unsigned short* kT = (unsigned short*)p; p += (size_t)B * TCe * 2;
  unsigned short* vb = (unsigned short*)p; p += (size_t)B * TCe * 2;
  unsigned short* aT = (unsigned short*)p; p += (size_t)B * TCe * 2;
  float* gmean = (float*)p; p += 512;
  float* grstd = (float*)p; p += 512;
  float* pl = (float*)p; p += (size_t)8 * B * T * 4;
  float* ra = (float*)p; p += (size_t)B * T * 4;

  // 1) GroupNorm
  gn_stats_k<<<B * 32, 256, 0, stream>>>(x, gmean, grstd);
  gn_apply_t_k<<<dim3(T / 64, C / 64, B), 256, 0, stream>>>(x, gns, gnb, gmean, grstd, hT);

  // 2) q,k projections (q folded with C^-0.5 = 1/16); 128x64 blocks share B
  gemm64x2_k<true, EPI_WT><<<dim3(T / 64, 2, B), 256, 0, stream>>>(
      wq, 0, C, hT, TCe, C, qT, TCe, C, bq, nullptr, 0, 0.0625f, C);
  gemm64x2_k<true, EPI_WT><<<dim3(T / 64, 2, B), 256, 0, stream>>>(
      wk, 0, C, hT, TCe, C, kT, TCe, C, bk, nullptr, 0, 1.0f, C);

  // 3) softmax denominators, then v projection pre-scaled by r (column scale)
  attn_stats3_k<<<dim3(T / 256, 8, B), 256, 0, stream>>>(qT, kT, pl);
  make_r_k<<<B * T / 256, 256, 0, stream>>>(pl, ra);
  gemm64x2_k<true, EPI_PBR><<<dim3(T / 64, 2, B), 256, 0, stream>>>(
      wvp, 0, C, hT, TCe, C, vb, TCe, T, bv, ra, T, 1.0f, C);

  // 4) fused S-recompute + exp + PV (R11 structure, r pre-folded)
  attn_pv6_k<<<256, 512, 0, stream>>>(qT, kT, vb, aT);

  // 5) final projection + bias + residual
  gemm64x2_k<true, EPI_FIN><<<dim3(T / 64, 2, B), 256, 0, stream>>>(
      wo, 0, C, aT, TCe, C, out, TCe, T, bo, x, TCe, 1.0f, C);
}

// Round 21
// 206.604 us; speedup vs baseline: 1.0246x; 1.0246x over previous
//
#include <hip/hip_runtime.h>

typedef float f32x4 __attribute__((ext_vector_type(4)));
typedef short s16x8 __attribute__((ext_vector_type(8)));

#define MOFF 12.0f

__device__ __forceinline__ unsigned short f2bf(float f) {
  unsigned int u = __float_as_uint(f);
  u += 0x7fffu + ((u >> 16) & 1u);
  return (unsigned short)(u >> 16);
}

template <typename T>
__device__ __forceinline__ void gload16(const T* g, T* l) {
  __builtin_amdgcn_global_load_lds(
      (const __attribute__((address_space(1))) void*)g,
      (__attribute__((address_space(3))) void*)l, 16, 0, 0);
}

// ---------------- GroupNorm stats: one block per (b,g) ----------------
__global__ __launch_bounds__(256) void gn_stats_k(const float* __restrict__ x,
                                                  float* __restrict__ meanv,
                                                  float* __restrict__ rstdv) {
  const int bg = blockIdx.x;
  const float4* base = (const float4*)(x + (size_t)bg * 8 * 4096);
  float s = 0.f, q = 0.f;
  for (int i = threadIdx.x; i < 8192; i += 256) {
    float4 v = base[i];
    s += v.x + v.y + v.z + v.w;
    q += v.x * v.x + v.y * v.y + v.z * v.z + v.w * v.w;
  }
  for (int o = 32; o; o >>= 1) { s += __shfl_down(s, o); q += __shfl_down(q, o); }
  __shared__ float ss[4], sq[4];
  const int wv = threadIdx.x >> 6;
  if ((threadIdx.x & 63) == 0) { ss[wv] = s; sq[wv] = q; }
  __syncthreads();
  if (threadIdx.x == 0) {
    s = ss[0] + ss[1] + ss[2] + ss[3];
    q = sq[0] + sq[1] + sq[2] + sq[3];
    float mu = s * (1.f / 32768.f);
    float var = q * (1.f / 32768.f) - mu * mu;
    meanv[bg] = mu;
    rstdv[bg] = rsqrtf(var + 1e-6f);
  }
}

// ------------- GroupNorm apply + transpose: write hT[b][t][c] bf16 -------------
__global__ __launch_bounds__(256) void gn_apply_t_k(const float* __restrict__ x,
    const float* __restrict__ gamma, const float* __restrict__ beta,
    const float* __restrict__ meanv, const float* __restrict__ rstdv,
    unsigned short* __restrict__ hT) {
  __shared__ unsigned short tile[64][72];
  const int b = blockIdx.z, c0 = blockIdx.y * 64, t0 = blockIdx.x * 64;
  const int tid = threadIdx.x;
  {
    const int tr = tid >> 4, tc = (tid & 15) * 4;
    const float* xb = x + ((size_t)b * 256 + c0) * 4096 + t0;
    for (int p2 = 0; p2 < 4; ++p2) {
      int cl = p2 * 16 + tr;
      int c = c0 + cl;
      int bg = b * 32 + (c >> 3);
      float ga = gamma[c] * rstdv[bg];
      float be = beta[c] - meanv[bg] * ga;
      float4 v = *(const float4*)(xb + (size_t)cl * 4096 + tc);
      tile[cl][tc + 0] = f2bf(v.x * ga + be);
      tile[cl][tc + 1] = f2bf(v.y * ga + be);
      tile[cl][tc + 2] = f2bf(v.z * ga + be);
      tile[cl][tc + 3] = f2bf(v.w * ga + be);
    }
  }
  __syncthreads();
  {
    const int orow = tid >> 3, oc = (tid & 7) * 8;
    unsigned short* hb = hT + ((size_t)b * 4096 + t0) * 256 + c0;
    for (int p2 = 0; p2 < 2; ++p2) {
      int tl = p2 * 32 + orow;
      s16x8 w;
#pragma unroll
      for (int j = 0; j < 8; ++j) w[j] = (short)tile[oc + j][tl];
      *(s16x8*)(hb + (size_t)tl * 256 + oc) = w;
    }
  }
}

// ---------------- generic 64x64-tile MFMA GEMM (projections) ----------------
enum { EPI_WT = 0, EPI_PB = 1, EPI_FIN = 3, EPI_PBR = 4 };

template <bool AF32, int EPI>
__global__ __launch_bounds__(256) void gemm64_k(
    const void* __restrict__ Ap, long long sA, int lda,
    const unsigned short* __restrict__ Bp, long long sB, int ldb,
    void* __restrict__ Op, long long sO, int ldo,
    const float* __restrict__ bias,
    const float* __restrict__ xadd, long long sX,
    float scale, int K) {
  __shared__ s16x8 lsA[4][64];
  __shared__ s16x8 lsB[4][64];
  const int tid = threadIdx.x;
  const int m0 = blockIdx.y * 64, n0 = blockIdx.x * 64;
  const int z = blockIdx.z;
  const int lane = tid & 63, wv = tid >> 6;
  const int lrow = lane & 15, lg = lane >> 4;
  const int srow = tid >> 2, scg = tid & 3;
  const int swrow = srow ^ (scg << 1);

  f32x4 acc[4];
#pragma unroll
  for (int i = 0; i < 4; ++i) acc[i] = (f32x4){0.f, 0.f, 0.f, 0.f};

  const unsigned short* Bb = Bp + (size_t)z * sB + (size_t)(n0 + srow) * ldb + scg * 8;

  for (int k0 = 0; k0 < K; k0 += 32) {
    if (AF32) {
      const float* ap = (const float*)Ap + (size_t)z * sA + (size_t)(m0 + srow) * lda + k0 + scg * 8;
      float4 v0 = *(const float4*)ap;
      float4 v1 = *(const float4*)(ap + 4);
      s16x8 w;
      w[0] = (short)f2bf(v0.x); w[1] = (short)f2bf(v0.y);
      w[2] = (short)f2bf(v0.z); w[3] = (short)f2bf(v0.w);
      w[4] = (short)f2bf(v1.x); w[5] = (short)f2bf(v1.y);
      w[6] = (short)f2bf(v1.z); w[7] = (short)f2bf(v1.w);
      lsA[scg][swrow] = w;
    } else {
      const unsigned short* ap = (const unsigned short*)Ap + (size_t)z * sA + (size_t)(m0 + srow) * lda + k0 + scg * 8;
      lsA[scg][swrow] = *(const s16x8*)ap;
    }
    lsB[scg][swrow] = *(const s16x8*)(Bb + k0);
    __syncthreads();
    s16x8 af = lsA[lg][(wv * 16 + lrow) ^ (lg << 1)];
#pragma unroll
    for (int nt = 0; nt < 4; ++nt) {
      s16x8 bf = lsB[lg][(nt * 16 + lrow) ^ (lg << 1)];
      acc[nt] = __builtin_amdgcn_mfma_f32_16x16x32_bf16(af, bf, acc[nt], 0, 0, 0);
    }
    __syncthreads();
  }

  const int mb = m0 + wv * 16 + lg * 4;
  float bv0 = 0.f, bv1 = 0.f, bv2 = 0.f, bv3 = 0.f;
  if (bias) { bv0 = bias[mb]; bv1 = bias[mb + 1]; bv2 = bias[mb + 2]; bv3 = bias[mb + 3]; }
#pragma unroll
  for (int nt = 0; nt < 4; ++nt) {
    const int n = n0 + nt * 16 + lrow;
    if (EPI == EPI_WT) {
      ushort4 pk;
      pk.x = f2bf((acc[nt][0] + bv0) * scale);
      pk.y = f2bf((acc[nt][1] + bv1) * scale);
      pk.z = f2bf((acc[nt][2] + bv2) * scale);
      pk.w = f2bf((acc[nt][3] + bv3) * scale);
      *(ushort4*)((unsigned short*)Op + (size_t)z * sO + (size_t)n * ldo + mb) = pk;
    } else if (EPI == EPI_PB) {
      unsigned short* o = (unsigned short*)Op + (size_t)z * sO;
      o[(size_t)(mb + 0) * ldo + n] = f2bf(acc[nt][0] + bv0);
      o[(size_t)(mb + 1) * ldo + n] = f2bf(acc[nt][1] + bv1);
      o[(size_t)(mb + 2) * ldo + n] = f2bf(acc[nt][2] + bv2);
      o[(size_t)(mb + 3) * ldo + n] = f2bf(acc[nt][3] + bv3);
    } else if (EPI == EPI_PBR) {
      unsigned short* o = (unsigned short*)Op + (size_t)z * sO;
      const float rc = (xadd + (size_t)z * sX)[n];
      o[(size_t)(mb + 0) * ldo + n] = f2bf((acc[nt][0] + bv0) * rc);
      o[(size_t)(mb + 1) * ldo + n] = f2bf((acc[nt][1] + bv1) * rc);
      o[(size_t)(mb + 2) * ldo + n] = f2bf((acc[nt][2] + bv2) * rc);
      o[(size_t)(mb + 3) * ldo + n] = f2bf((acc[nt][3] + bv3) * rc);
    } else {
      float* o = (float*)Op + (size_t)z * sO;
      const float* xa = xadd + (size_t)z * sX;
      o[(size_t)(mb + 0) * ldo + n] = acc[nt][0] + bv0 + xa[(size_t)(mb + 0) * ldo + n];
      o[(size_t)(mb + 1) * ldo + n] = acc[nt][1] + bv1 + xa[(size_t)(mb + 1) * ldo + n];
      o[(size_t)(mb + 2) * ldo + n] = acc[nt][2] + bv2 + xa[(size_t)(mb + 2) * ldo + n];
      o[(size_t)(mb + 3) * ldo + n] = acc[nt][3] + bv3 + xa[(size_t)(mb + 3) * ldo + n];
    }
  }
}

// ------- pass 1: l[q] = sum_k exp(S - MOFF), fixed offset, no max tracking -------
__global__ __launch_bounds__(256) void attn_stats3_k(
    const unsigned short* __restrict__ qT,
    const unsigned short* __restrict__ kT,
    float* __restrict__ pl) {  // [8][B][T] partial sums
  __shared__ unsigned short kbuf[2][64 * 256];
  const int tid = threadIdx.x;
  const int b = blockIdx.z;
  const int Q0 = blockIdx.x * 256;
  const int kc = blockIdx.y;
  const int lane = tid & 63, wq = tid >> 6;
  const int lrow = lane & 15, lg = lane >> 4;

  const unsigned short* qb = qT + (size_t)b * (4096 * 256);
  const unsigned short* kb = kT + (size_t)b * (4096 * 256);

  s16x8 af[4][8];
#pragma unroll
  for (int mt = 0; mt < 4; ++mt)
#pragma unroll
    for (int ks = 0; ks < 8; ++ks)
      af[mt][ks] = *(const s16x8*)(qb + (size_t)(Q0 + wq * 64 + mt * 16 + lrow) * 256 + ks * 32 + lg * 8);

  float sl[4][4];
#pragma unroll
  for (int mt = 0; mt < 4; ++mt)
#pragma unroll
    for (int j = 0; j < 4; ++j) sl[mt][j] = 0.f;

  int cur = 0;
  {
    const unsigned short* src = kb + (size_t)(kc * 512) * 256;
#pragma unroll
    for (int rep = 0; rep < 8; ++rep) {
      int i = rep * 256 + tid;
      int row = i >> 5, c8 = i & 31;
      gload16(src + (size_t)row * 256 + (c8 ^ (row & 7)) * 8, &kbuf[0][(i - lane) * 8]);
    }
  }
  __syncthreads();

  for (int it = 0; it < 8; ++it) {
    if (it + 1 < 8) {
      const unsigned short* src = kb + (size_t)(kc * 512 + (it + 1) * 64) * 256;
#pragma unroll
      for (int rep = 0; rep < 8; ++rep) {
        int i = rep * 256 + tid;
        int row = i >> 5, c8 = i & 31;
        gload16(src + (size_t)row * 256 + (c8 ^ (row & 7)) * 8, &kbuf[cur ^ 1][(i - lane) * 8]);
      }
    }
#pragma unroll
    for (int nt = 0; nt < 4; ++nt) {
      f32x4 acc[4];
#pragma unroll
      for (int mt = 0; mt < 4; ++mt) acc[mt] = (f32x4){0.f, 0.f, 0.f, 0.f};
#pragma unroll
      for (int ks = 0; ks < 8; ++ks) {
        int row = nt * 16 + lrow;
        int ch = (ks * 4 + lg) ^ (row & 7);
        s16x8 bf = *(const s16x8*)&kbuf[cur][row * 256 + ch * 8];
#pragma unroll
        for (int mt = 0; mt < 4; ++mt)
          acc[mt] = __builtin_amdgcn_mfma_f32_16x16x32_bf16(af[mt][ks], bf, acc[mt], 0, 0, 0);
      }
#pragma unroll
      for (int mt = 0; mt < 4; ++mt)
#pragma unroll
        for (int j = 0; j < 4; ++j) sl[mt][j] += __expf(acc[mt][j] - MOFF);
    }
    __syncthreads();
    cur ^= 1;
  }
#pragma unroll
  for (int mt = 0; mt < 4; ++mt)
#pragma unroll
    for (int j = 0; j < 4; ++j) {
      float v = sl[mt][j];
      v += __shfl_xor(v, 1);
      v += __shfl_xor(v, 2);
      v += __shfl_xor(v, 4);
      v += __shfl_xor(v, 8);
      sl[mt][j] = v;
    }
  if (lrow == 0) {
    float* plb = pl + ((size_t)kc * 4 + b) * 4096;
#pragma unroll
    for (int mt = 0; mt < 4; ++mt)
#pragma unroll
      for (int j = 0; j < 4; ++j)
        plb[Q0 + wq * 64 + mt * 16 + lg * 4 + j] = sl[mt][j];
  }
}

__global__ __launch_bounds__(256) void make_r_k(const float* __restrict__ pl,
                                                float* __restrict__ ra) {
  int i = blockIdx.x * 256 + threadIdx.x;
  int b = i >> 12, q = i & 4095;
  float l = 0.f;
#pragma unroll
  for (int kc = 0; kc < 8; ++kc) l += pl[((size_t)kc * 4 + b) * 4096 + q];
  ra[i] = 1.f / l;
}

// ------- pass 2 v6: fused S-recompute + exp + PV (r pre-folded into v) -------
// grid 256 (1/CU), 512 thr. Block owns k-tile [K0,K0+64) of batch z; q in tiles of 128.
__global__ __launch_bounds__(512) void attn_pv6_k(
    const unsigned short* __restrict__ qT,
    const unsigned short* __restrict__ kT,
    const unsigned short* __restrict__ vt,   // v*r [B][C][T]
    unsigned short* __restrict__ aT) {       // [B][T][C]
  __shared__ unsigned short qbuf[2][128 * 256];  // 64KB x2
  __shared__ unsigned short P[64 * 128];         // 16KB, chunk-XOR swizzled
  const int tid = threadIdx.x;
  const int pidx = blockIdx.x;
  const int z = (pidx >> 1) & 3;                       // batch -> XCD pair
  const int kt = ((pidx >> 3) << 1) | (pidx & 1);      // 0..63
  const int K0 = kt * 64;
  const int lane = tid & 63, w = tid >> 6;
  const int lrow = lane & 15, lg = lane >> 4;
  const int khw = w >> 2;   // k-half (32 rows) this wave computes in S phase
  const int qqw = w & 3;    // q-quarter (32 cols) this wave computes in S phase

  const unsigned short* qg = qT + (size_t)z * (4096 * 256);
  const unsigned short* kg = kT + (size_t)z * (4096 * 256);
  const unsigned short* vg = vt + (size_t)z * (4096 * 256);

  // pinned kf: A-operand rows K0+khw*32 .. +32 (2 tiles x 8 ks)
  s16x8 kf[2][8];
#pragma unroll
  for (int ktl = 0; ktl < 2; ++ktl)
#pragma unroll
    for (int ks = 0; ks < 8; ++ks)
      kf[ktl][ks] = *(const s16x8*)(kg + (size_t)(K0 + khw * 32 + ktl * 16 + lrow) * 256 + ks * 32 + lg * 8);

  f32x4 oacc[2][4];  // out c-tiles (w*32 + ct*16) x k-tiles (nt*16)
#pragma unroll
  for (int ct = 0; ct < 2; ++ct)
#pragma unroll
    for (int nt = 0; nt < 4; ++nt) oacc[ct][nt] = (f32x4){0.f, 0.f, 0.f, 0.f};

  int cur = 0;
  {  // prologue: stage q-tile 0 (128 rows x 512B), pre-swizzled source
#pragma unroll
    for (int rep = 0; rep < 8; ++rep) {
      int i = rep * 512 + tid;
      int row = i >> 5, c8 = i & 31;
      gload16(qg + (size_t)row * 256 + (c8 ^ (row & 7)) * 8, &qbuf[0][(i - lane) * 8]);
    }
  }
  __syncthreads();

  for (int qi = 0; qi < 32; ++qi) {
    const int q0 = qi * 128;
    // v fragments for this iter's PV: global -> reg, in flight through S phase
    s16x8 vf[2][4];
#pragma unroll
    for (int ct = 0; ct < 2; ++ct)
#pragma unroll
      for (int qs = 0; qs < 4; ++qs)
        vf[ct][qs] = *(const s16x8*)(vg + (size_t)(w * 32 + ct * 16 + lrow) * 4096 + q0 + qs * 32 + lg * 8);
    // stage next q-tile
    if (qi + 1 < 32) {
      const unsigned short* src = qg + (size_t)(q0 + 128) * 256;
#pragma unroll
      for (int rep = 0; rep < 8; ++rep) {
        int i = rep * 512 + tid;
        int row = i >> 5, c8 = i & 31;
        gload16(src + (size_t)row * 256 + (c8 ^ (row & 7)) * 8, &qbuf[cur ^ 1][(i - lane) * 8]);
      }
    }
    // S phase: S^T quadrant [khw*32 .. +32][qqw*32 .. +32]
    f32x4 sacc[2][2];
#pragma unroll
    for (int ktl = 0; ktl < 2; ++ktl)
#pragma unroll
      for (int qt = 0; qt < 2; ++qt) sacc[ktl][qt] = (f32x4){0.f, 0.f, 0.f, 0.f};
#pragma unroll
    for (int qt = 0; qt < 2; ++qt) {
#pragma unroll
      for (int ks = 0; ks < 8; ++ks) {
        int row = qqw * 32 + qt * 16 + lrow;
        int ch = (ks * 4 + lg) ^ (row & 7);
        s16x8 qf = *(const s16x8*)&qbuf[cur][row * 256 + ch * 8];
        sacc[0][qt] = __builtin_amdgcn_mfma_f32_16x16x32_bf16(kf[0][ks], qf, sacc[0][qt], 0, 0, 0);
        sacc[1][qt] = __builtin_amdgcn_mfma_f32_16x16x32_bf16(kf[1][ks], qf, sacc[1][qt], 0, 0, 0);
      }
    }
    // exp and write P (bf16), swizzled: elem (k,q) at short index k*128 + ((q>>3)^(k&7))*8 + (q&7)
#pragma unroll
    for (int qt = 0; qt < 2; ++qt) {
      const int ql = qqw * 32 + qt * 16 + lrow;
#pragma unroll
      for (int ktl = 0; ktl < 2; ++ktl)
#pragma unroll
        for (int j = 0; j < 4; ++j) {
          int k = khw * 32 + ktl * 16 + lg * 4 + j;
          float p = __expf(sacc[ktl][qt][j] - MOFF);
          P[k * 128 + (((ql >> 3) ^ (k & 7)) << 3) + (ql & 7)] = f2bf(p);
        }
    }
    __syncthreads();  // P visible; next q-tile staged (vmcnt drained)
    // PV: oacc[c][k] += vtilde[c][q-tile] * P^T[k][q-tile]
#pragma unroll
    for (int qs = 0; qs < 4; ++qs) {
      s16x8 pf[4];
#pragma unroll
      for (int nt = 0; nt < 4; ++nt) {
        int k = nt * 16 + lrow;
        pf[nt] = *(const s16x8*)&P[k * 128 + (((qs * 4 + lg) ^ (k & 7)) << 3)];
      }
#pragma unroll
      for (int ct = 0; ct < 2; ++ct)
#pragma unroll
        for (int nt = 0; nt < 4; ++nt)
          oacc[ct][nt] = __builtin_amdgcn_mfma_f32_16x16x32_bf16(vf[ct][qs], pf[nt], oacc[ct][nt], 0, 0, 0);
    }
    __syncthreads();  // P consumed; safe to overwrite next iter
    cur ^= 1;
  }
  // epilogue: aT[z][K0+k][c]
  unsigned short* ab = aT + (size_t)z * (4096 * 256);
#pragma unroll
  for (int ct = 0; ct < 2; ++ct)
#pragma unroll
    for (int nt = 0; nt < 4; ++nt) {
      int k = K0 + nt * 16 + lrow;
      int c = w * 32 + ct * 16 + lg * 4;
      ushort4 pk;
      pk.x = f2bf(oacc[ct][nt][0]);
      pk.y = f2bf(oacc[ct][nt][1]);
      pk.z = f2bf(oacc[ct][nt][2]);
      pk.w = f2bf(oacc[ct][nt][3]);
      *(ushort4*)(ab + (size_t)k * 256 + c) = pk;
    }
}

extern "C" void kernel_launch(void* const* d_in, const int* in_sizes, int n_in,
                              void* d_out, int out_size, void* d_ws, size_t ws_size,
                              hipStream_t stream) {
  const float* x   = (const float*)d_in[0];
  const float* gns = (const float*)d_in[1];
  const float* gnb = (const float*)d_in[2];
  const float* wq  = (const float*)d_in[3];
  const float* bq  = (const float*)d_in[4];
  const float* wk  = (const float*)d_in[5];
  const float* bk  = (const float*)d_in[6];
  const float* wvp = (const float*)d_in[7];
  const float* bv  = (const float*)d_in[8];
  const float* wo  = (const float*)d_in[9];
  const float* bo  = (const float*)d_in[10];
  float* out = (float*)d_out;

  const int B = 4, C = 256, T = 4096;
  const long long TCe = (long long)T * C;

  char* p = (char*)d_ws;
  unsigned short* hT = (unsigned short*)p; p += (size_t)B * TCe * 2;
  unsigned short* qT = (unsigned short*)p; p += (size_t)B * TCe * 2;
  unsigned short* kT = (unsigned short*)p; p += (size_t)B * TCe * 2;
  unsigned short* vb = (unsigned short*)p; p += (size_t)B * TCe * 2;
  unsigned short* aT = (unsigned short*)p; p += (size_t)B * TCe * 2;
  float* gmean = (float*)p; p += 512;
  float* grstd = (float*)p; p += 512;
  float* pl = (float*)p; p += (size_t)8 * B * T * 4;
  float* ra = (float*)p; p += (size_t)B * T * 4;

  // 1) GroupNorm
  gn_stats_k<<<B * 32, 256, 0, stream>>>(x, gmean, grstd);
  gn_apply_t_k<<<dim3(T / 64, C / 64, B), 256, 0, stream>>>(x, gns, gnb, gmean, grstd, hT);

  // 2) q,k projections (q folded with C^-0.5 = 1/16)
  gemm64_k<true, EPI_WT><<<dim3(T / 64, C / 64, B), 256, 0, stream>>>(
      wq, 0, C, hT, TCe, C, qT, TCe, C, bq, nullptr, 0, 0.0625f, C);
  gemm64_k<true, EPI_WT><<<dim3(T / 64, C / 64, B), 256, 0, stream>>>(
      wk, 0, C, hT, TCe, C, kT, TCe, C, bk, nullptr, 0, 1.0f, C);

  // 3) softmax denominators, then v projection pre-scaled by r (column scale)
  attn_stats3_k<<<dim3(T / 256, 8, B), 256, 0, stream>>>(qT, kT, pl);
  make_r_k<<<B * T / 256, 256, 0, stream>>>(pl, ra);
  gemm64_k<true, EPI_PBR><<<dim3(T / 64, C / 64, B), 256, 0, stream>>>(
      wvp, 0, C, hT, TCe, C, vb, TCe, T, bv, ra, T, 1.0f, C);

  // 4) fused S-recompute + exp + PV (R11 structure, r pre-folded)
  attn_pv6_k<<<256, 512, 0, stream>>>(qT, kT, vb, aT);

  // 5) final projection + bias + residual
  gemm64_k<true, EPI_FIN><<<dim3(T / 64, C / 64, B), 256, 0, stream>>>(
      wo, 0, C, aT, TCe, C, out, TCe, T, bo, x, TCe, 1.0f, C);
}

// Round 22
// 185.050 us; speedup vs baseline: 1.1439x; 1.1165x over previous
//
#include <hip/hip_runtime.h>

typedef float f32x4 __attribute__((ext_vector_type(4)));
typedef short s16x8 __attribute__((ext_vector_type(8)));

#define MOFF 12.0f

__device__ __forceinline__ unsigned short f2bf(float f) {
  unsigned int u = __float_as_uint(f);
  u += 0x7fffu + ((u >> 16) & 1u);
  return (unsigned short)(u >> 16);
}

template <typename T>
__device__ __forceinline__ void gload16(const T* g, T* l) {
  __builtin_amdgcn_global_load_lds(
      (const __attribute__((address_space(1))) void*)g,
      (__attribute__((address_space(3))) void*)l, 16, 0, 0);
}

// ---------------- GroupNorm stats: one block per (b,g) ----------------
__global__ __launch_bounds__(256) void gn_stats_k(const float* __restrict__ x,
                                                  float* __restrict__ meanv,
                                                  float* __restrict__ rstdv) {
  const int bg = blockIdx.x;
  const float4* base = (const float4*)(x + (size_t)bg * 8 * 4096);
  float s = 0.f, q = 0.f;
  for (int i = threadIdx.x; i < 8192; i += 256) {
    float4 v = base[i];
    s += v.x + v.y + v.z + v.w;
    q += v.x * v.x + v.y * v.y + v.z * v.z + v.w * v.w;
  }
  for (int o = 32; o; o >>= 1) { s += __shfl_down(s, o); q += __shfl_down(q, o); }
  __shared__ float ss[4], sq[4];
  const int wv = threadIdx.x >> 6;
  if ((threadIdx.x & 63) == 0) { ss[wv] = s; sq[wv] = q; }
  __syncthreads();
  if (threadIdx.x == 0) {
    s = ss[0] + ss[1] + ss[2] + ss[3];
    q = sq[0] + sq[1] + sq[2] + sq[3];
    float mu = s * (1.f / 32768.f);
    float var = q * (1.f / 32768.f) - mu * mu;
    meanv[bg] = mu;
    rstdv[bg] = rsqrtf(var + 1e-6f);
  }
}

// ------------- GroupNorm apply + transpose: write hT[b][t][c] bf16 -------------
__global__ __launch_bounds__(256) void gn_apply_t_k(const float* __restrict__ x,
    const float* __restrict__ gamma, const float* __restrict__ beta,
    const float* __restrict__ meanv, const float* __restrict__ rstdv,
    unsigned short* __restrict__ hT) {
  __shared__ unsigned short tile[64][72];
  const int b = blockIdx.z, c0 = blockIdx.y * 64, t0 = blockIdx.x * 64;
  const int tid = threadIdx.x;
  {
    const int tr = tid >> 4, tc = (tid & 15) * 4;
    const float* xb = x + ((size_t)b * 256 + c0) * 4096 + t0;
    for (int p2 = 0; p2 < 4; ++p2) {
      int cl = p2 * 16 + tr;
      int c = c0 + cl;
      int bg = b * 32 + (c >> 3);
      float ga = gamma[c] * rstdv[bg];
      float be = beta[c] - meanv[bg] * ga;
      float4 v = *(const float4*)(xb + (size_t)cl * 4096 + tc);
      tile[cl][tc + 0] = f2bf(v.x * ga + be);
      tile[cl][tc + 1] = f2bf(v.y * ga + be);
      tile[cl][tc + 2] = f2bf(v.z * ga + be);
      tile[cl][tc + 3] = f2bf(v.w * ga + be);
    }
  }
  __syncthreads();
  {
    const int orow = tid >> 3, oc = (tid & 7) * 8;
    unsigned short* hb = hT + ((size_t)b * 4096 + t0) * 256 + c0;
    for (int p2 = 0; p2 < 2; ++p2) {
      int tl = p2 * 32 + orow;
      s16x8 w;
#pragma unroll
      for (int j = 0; j < 8; ++j) w[j] = (short)tile[oc + j][tl];
      *(s16x8*)(hb + (size_t)tl * 256 + oc) = w;
    }
  }
}

// ---------------- generic 64x64-tile MFMA GEMM (projections) ----------------
enum { EPI_WT = 0, EPI_PB = 1, EPI_FIN = 3, EPI_PBR = 4 };

template <bool AF32, int EPI>
__global__ __launch_bounds__(256) void gemm64_k(
    const void* __restrict__ Ap, long long sA, int lda,
    const unsigned short* __restrict__ Bp, long long sB, int ldb,
    void* __restrict__ Op, long long sO, int ldo,
    const float* __restrict__ bias,
    const float* __restrict__ xadd, long long sX,
    float scale, int K) {
  __shared__ s16x8 lsA[4][64];
  __shared__ s16x8 lsB[4][64];
  const int tid = threadIdx.x;
  const int m0 = blockIdx.y * 64, n0 = blockIdx.x * 64;
  const int z = blockIdx.z;
  const int lane = tid & 63, wv = tid >> 6;
  const int lrow = lane & 15, lg = lane >> 4;
  const int srow = tid >> 2, scg = tid & 3;
  const int swrow = srow ^ (scg << 1);

  f32x4 acc[4];
#pragma unroll
  for (int i = 0; i < 4; ++i) acc[i] = (f32x4){0.f, 0.f, 0.f, 0.f};

  const unsigned short* Bb = Bp + (size_t)z * sB + (size_t)(n0 + srow) * ldb + scg * 8;

  for (int k0 = 0; k0 < K; k0 += 32) {
    if (AF32) {
      const float* ap = (const float*)Ap + (size_t)z * sA + (size_t)(m0 + srow) * lda + k0 + scg * 8;
      float4 v0 = *(const float4*)ap;
      float4 v1 = *(const float4*)(ap + 4);
      s16x8 w;
      w[0] = (short)f2bf(v0.x); w[1] = (short)f2bf(v0.y);
      w[2] = (short)f2bf(v0.z); w[3] = (short)f2bf(v0.w);
      w[4] = (short)f2bf(v1.x); w[5] = (short)f2bf(v1.y);
      w[6] = (short)f2bf(v1.z); w[7] = (short)f2bf(v1.w);
      lsA[scg][swrow] = w;
    } else {
      const unsigned short* ap = (const unsigned short*)Ap + (size_t)z * sA + (size_t)(m0 + srow) * lda + k0 + scg * 8;
      lsA[scg][swrow] = *(const s16x8*)ap;
    }
    lsB[scg][swrow] = *(const s16x8*)(Bb + k0);
    __syncthreads();
    s16x8 af = lsA[lg][(wv * 16 + lrow) ^ (lg << 1)];
#pragma unroll
    for (int nt = 0; nt < 4; ++nt) {
      s16x8 bf = lsB[lg][(nt * 16 + lrow) ^ (lg << 1)];
      acc[nt] = __builtin_amdgcn_mfma_f32_16x16x32_bf16(af, bf, acc[nt], 0, 0, 0);
    }
    __syncthreads();
  }

  const int mb = m0 + wv * 16 + lg * 4;
  float bv0 = 0.f, bv1 = 0.f, bv2 = 0.f, bv3 = 0.f;
  if (bias) { bv0 = bias[mb]; bv1 = bias[mb + 1]; bv2 = bias[mb + 2]; bv3 = bias[mb + 3]; }
#pragma unroll
  for (int nt = 0; nt < 4; ++nt) {
    const int n = n0 + nt * 16 + lrow;
    if (EPI == EPI_WT) {
      ushort4 pk;
      pk.x = f2bf((acc[nt][0] + bv0) * scale);
      pk.y = f2bf((acc[nt][1] + bv1) * scale);
      pk.z = f2bf((acc[nt][2] + bv2) * scale);
      pk.w = f2bf((acc[nt][3] + bv3) * scale);
      *(ushort4*)((unsigned short*)Op + (size_t)z * sO + (size_t)n * ldo + mb) = pk;
    } else if (EPI == EPI_PB) {
      unsigned short* o = (unsigned short*)Op + (size_t)z * sO;
      o[(size_t)(mb + 0) * ldo + n] = f2bf(acc[nt][0] + bv0);
      o[(size_t)(mb + 1) * ldo + n] = f2bf(acc[nt][1] + bv1);
      o[(size_t)(mb + 2) * ldo + n] = f2bf(acc[nt][2] + bv2);
      o[(size_t)(mb + 3) * ldo + n] = f2bf(acc[nt][3] + bv3);
    } else if (EPI == EPI_PBR) {
      unsigned short* o = (unsigned short*)Op + (size_t)z * sO;
      const float rc = (xadd + (size_t)z * sX)[n];
      o[(size_t)(mb + 0) * ldo + n] = f2bf((acc[nt][0] + bv0) * rc);
      o[(size_t)(mb + 1) * ldo + n] = f2bf((acc[nt][1] + bv1) * rc);
      o[(size_t)(mb + 2) * ldo + n] = f2bf((acc[nt][2] + bv2) * rc);
      o[(size_t)(mb + 3) * ldo + n] = f2bf((acc[nt][3] + bv3) * rc);
    } else {
      float* o = (float*)Op + (size_t)z * sO;
      const float* xa = xadd + (size_t)z * sX;
      o[(size_t)(mb + 0) * ldo + n] = acc[nt][0] + bv0 + xa[(size_t)(mb + 0) * ldo + n];
      o[(size_t)(mb + 1) * ldo + n] = acc[nt][1] + bv1 + xa[(size_t)(mb + 1) * ldo + n];
      o[(size_t)(mb + 2) * ldo + n] = acc[nt][2] + bv2 + xa[(size_t)(mb + 2) * ldo + n];
      o[(size_t)(mb + 3) * ldo + n] = acc[nt][3] + bv3 + xa[(size_t)(mb + 3) * ldo + n];
    }
  }
}

// ------- pass 1: l[q] = sum_k exp(S - MOFF), fixed offset, no max tracking -------
__global__ __launch_bounds__(256) void attn_stats3_k(
    const unsigned short* __restrict__ qT,
    const unsigned short* __restrict__ kT,
    float* __restrict__ pl) {  // [8][B][T] partial sums
  __shared__ unsigned short kbuf[2][64 * 256];
  const int tid = threadIdx.x;
  const int b = blockIdx.z;
  const int Q0 = blockIdx.x * 256;
  const int kc = blockIdx.y;
  const int lane = tid & 63, wq = tid >> 6;
  const int lrow = lane & 15, lg = lane >> 4;

  const unsigned short* qb = qT + (size_t)b * (4096 * 256);
  const unsigned short* kb = kT + (size_t)b * (4096 * 256);

  s16x8 af[4][8];
#pragma unroll
  for (int mt = 0; mt < 4; ++mt)
#pragma unroll
    for (int ks = 0; ks < 8; ++ks)
      af[mt][ks] = *(const s16x8*)(qb + (size_t)(Q0 + wq * 64 + mt * 16 + lrow) * 256 + ks * 32 + lg * 8);

  float sl[4][4];
#pragma unroll
  for (int mt = 0; mt < 4; ++mt)
#pragma unroll
    for (int j = 0; j < 4; ++j) sl[mt][j] = 0.f;

  int cur = 0;
  {
    const unsigned short* src = kb + (size_t)(kc * 512) * 256;
#pragma unroll
    for (int rep = 0; rep < 8; ++rep) {
      int i = rep * 256 + tid;
      int row = i >> 5, c8 = i & 31;
      gload16(src + (size_t)row * 256 + (c8 ^ (row & 7)) * 8, &kbuf[0][(i - lane) * 8]);
    }
  }
  __syncthreads();

  for (int it = 0; it < 8; ++it) {
    if (it + 1 < 8) {
      const unsigned short* src = kb + (size_t)(kc * 512 + (it + 1) * 64) * 256;
#pragma unroll
      for (int rep = 0; rep < 8; ++rep) {
        int i = rep * 256 + tid;
        int row = i >> 5, c8 = i & 31;
        gload16(src + (size_t)row * 256 + (c8 ^ (row & 7)) * 8, &kbuf[cur ^ 1][(i - lane) * 8]);
      }
    }
#pragma unroll
    for (int nt = 0; nt < 4; ++nt) {
      f32x4 acc[4];
#pragma unroll
      for (int mt = 0; mt < 4; ++mt) acc[mt] = (f32x4){0.f, 0.f, 0.f, 0.f};
#pragma unroll
      for (int ks = 0; ks < 8; ++ks) {
        int row = nt * 16 + lrow;
        int ch = (ks * 4 + lg) ^ (row & 7);
        s16x8 bf = *(const s16x8*)&kbuf[cur][row * 256 + ch * 8];
#pragma unroll
        for (int mt = 0; mt < 4; ++mt)
          acc[mt] = __builtin_amdgcn_mfma_f32_16x16x32_bf16(af[mt][ks], bf, acc[mt], 0, 0, 0);
      }
#pragma unroll
      for (int mt = 0; mt < 4; ++mt)
#pragma unroll
        for (int j = 0; j < 4; ++j) sl[mt][j] += __expf(acc[mt][j] - MOFF);
    }
    __syncthreads();
    cur ^= 1;
  }
#pragma unroll
  for (int mt = 0; mt < 4; ++mt)
#pragma unroll
    for (int j = 0; j < 4; ++j) {
      float v = sl[mt][j];
      v += __shfl_xor(v, 1);
      v += __shfl_xor(v, 2);
      v += __shfl_xor(v, 4);
      v += __shfl_xor(v, 8);
      sl[mt][j] = v;
    }
  if (lrow == 0) {
    float* plb = pl + ((size_t)kc * 4 + b) * 4096;
#pragma unroll
    for (int mt = 0; mt < 4; ++mt)
#pragma unroll
      for (int j = 0; j < 4; ++j)
        plb[Q0 + wq * 64 + mt * 16 + lg * 4 + j] = sl[mt][j];
  }
}

__global__ __launch_bounds__(256) void make_r_k(const float* __restrict__ pl,
                                                float* __restrict__ ra) {
  int i = blockIdx.x * 256 + threadIdx.x;
  int b = i >> 12, q = i & 4095;
  float l = 0.f;
#pragma unroll
  for (int kc = 0; kc < 8; ++kc) l += pl[((size_t)kc * 4 + b) * 4096 + q];
  ra[i] = 1.f / l;
}

// ------- pass 2 v6h: pv6 with double-buffered P and ONE barrier per iter -------
// grid 256 (1/CU), 512 thr. LDS = 128K qbuf + 32K P = 160 KiB exactly.
__global__ __launch_bounds__(512) void attn_pv6h_k(
    const unsigned short* __restrict__ qT,
    const unsigned short* __restrict__ kT,
    const unsigned short* __restrict__ vt,   // v*r [B][C][T]
    unsigned short* __restrict__ aT) {       // [B][T][C]
  __shared__ unsigned short qbuf[2][128 * 256];  // 64KB x2
  __shared__ unsigned short P[2][64 * 128];      // 16KB x2, chunk-XOR swizzled
  const int tid = threadIdx.x;
  const int pidx = blockIdx.x;
  const int z = (pidx >> 1) & 3;                       // batch -> XCD pair
  const int kt = ((pidx >> 3) << 1) | (pidx & 1);      // 0..63
  const int K0 = kt * 64;
  const int lane = tid & 63, w = tid >> 6;
  const int lrow = lane & 15, lg = lane >> 4;
  const int khw = w >> 2;   // k-half (32 rows) this wave computes in S phase
  const int qqw = w & 3;    // q-quarter (32 cols) this wave computes in S phase

  const unsigned short* qg = qT + (size_t)z * (4096 * 256);
  const unsigned short* kg = kT + (size_t)z * (4096 * 256);
  const unsigned short* vg = vt + (size_t)z * (4096 * 256);

  // pinned kf: A-operand rows K0+khw*32 .. +32 (2 tiles x 8 ks)
  s16x8 kf[2][8];
#pragma unroll
  for (int ktl = 0; ktl < 2; ++ktl)
#pragma unroll
    for (int ks = 0; ks < 8; ++ks)
      kf[ktl][ks] = *(const s16x8*)(kg + (size_t)(K0 + khw * 32 + ktl * 16 + lrow) * 256 + ks * 32 + lg * 8);

  f32x4 oacc[2][4];  // out c-tiles (w*32 + ct*16) x k-tiles (nt*16)
#pragma unroll
  for (int ct = 0; ct < 2; ++ct)
#pragma unroll
    for (int nt = 0; nt < 4; ++nt) oacc[ct][nt] = (f32x4){0.f, 0.f, 0.f, 0.f};

  int cur = 0;
  {  // prologue: stage q-tile 0 (128 rows x 512B), pre-swizzled source
#pragma unroll
    for (int rep = 0; rep < 8; ++rep) {
      int i = rep * 512 + tid;
      int row = i >> 5, c8 = i & 31;
      gload16(qg + (size_t)row * 256 + (c8 ^ (row & 7)) * 8, &qbuf[0][(i - lane) * 8]);
    }
  }
  __syncthreads();

  for (int qi = 0; qi < 32; ++qi) {
    const int q0 = qi * 128;
    const int pb = qi & 1;
    unsigned short* Pb = &P[pb][0];
    // v fragments for this iter's PV: global -> reg, in flight through S phase
    s16x8 vf[2][4];
#pragma unroll
    for (int ct = 0; ct < 2; ++ct)
#pragma unroll
      for (int qs = 0; qs < 4; ++qs)
        vf[ct][qs] = *(const s16x8*)(vg + (size_t)(w * 32 + ct * 16 + lrow) * 4096 + q0 + qs * 32 + lg * 8);
    // stage next q-tile
    if (qi + 1 < 32) {
      const unsigned short* src = qg + (size_t)(q0 + 128) * 256;
#pragma unroll
      for (int rep = 0; rep < 8; ++rep) {
        int i = rep * 512 + tid;
        int row = i >> 5, c8 = i & 31;
        gload16(src + (size_t)row * 256 + (c8 ^ (row & 7)) * 8, &qbuf[cur ^ 1][(i - lane) * 8]);
      }
    }
    // S phase: S^T quadrant [khw*32 .. +32][qqw*32 .. +32]
    f32x4 sacc[2][2];
#pragma unroll
    for (int ktl = 0; ktl < 2; ++ktl)
#pragma unroll
      for (int qt = 0; qt < 2; ++qt) sacc[ktl][qt] = (f32x4){0.f, 0.f, 0.f, 0.f};
#pragma unroll
    for (int qt = 0; qt < 2; ++qt) {
#pragma unroll
      for (int ks = 0; ks < 8; ++ks) {
        int row = qqw * 32 + qt * 16 + lrow;
        int ch = (ks * 4 + lg) ^ (row & 7);
        s16x8 qf = *(const s16x8*)&qbuf[cur][row * 256 + ch * 8];
        sacc[0][qt] = __builtin_amdgcn_mfma_f32_16x16x32_bf16(kf[0][ks], qf, sacc[0][qt], 0, 0, 0);
        sacc[1][qt] = __builtin_amdgcn_mfma_f32_16x16x32_bf16(kf[1][ks], qf, sacc[1][qt], 0, 0, 0);
      }
    }
    // exp and write P[pb] (bf16): elem (k,q) at k*128 + ((q>>3)^(k&7))*8 + (q&7)
#pragma unroll
    for (int qt = 0; qt < 2; ++qt) {
      const int ql = qqw * 32 + qt * 16 + lrow;
#pragma unroll
      for (int ktl = 0; ktl < 2; ++ktl)
#pragma unroll
        for (int j = 0; j < 4; ++j) {
          int k = khw * 32 + ktl * 16 + lg * 4 + j;
          float p = __expf(sacc[ktl][qt][j] - MOFF);
          Pb[k * 128 + (((ql >> 3) ^ (k & 7)) << 3) + (ql & 7)] = f2bf(p);
        }
    }
    __syncthreads();  // SINGLE barrier: P[pb] visible; own stage drained (vmcnt 0)
    // PV: oacc[c][k] += vtilde[c][q-tile] * P^T[k][q-tile]  (no trailing barrier:
    // next iter writes P[pb^1] and stages qbuf[cur], both disjoint from readers)
#pragma unroll
    for (int qs = 0; qs < 4; ++qs) {
      s16x8 pf[4];
#pragma unroll
      for (int nt = 0; nt < 4; ++nt) {
        int k = nt * 16 + lrow;
        pf[nt] = *(const s16x8*)&Pb[k * 128 + (((qs * 4 + lg) ^ (k & 7)) << 3)];
      }
#pragma unroll
      for (int ct = 0; ct < 2; ++ct)
#pragma unroll
        for (int nt = 0; nt < 4; ++nt)
          oacc[ct][nt] = __builtin_amdgcn_mfma_f32_16x16x32_bf16(vf[ct][qs], pf[nt], oacc[ct][nt], 0, 0, 0);
    }
    cur ^= 1;
  }
  // epilogue: aT[z][K0+k][c]
  unsigned short* ab = aT + (size_t)z * (4096 * 256);
#pragma unroll
  for (int ct = 0; ct < 2; ++ct)
#pragma unroll
    for (int nt = 0; nt < 4; ++nt) {
      int k = K0 + nt * 16 + lrow;
      int c = w * 32 + ct * 16 + lg * 4;
      ushort4 pk;
      pk.x = f2bf(oacc[ct][nt][0]);
      pk.y = f2bf(oacc[ct][nt][1]);
      pk.z = f2bf(oacc[ct][nt][2]);
      pk.w = f2bf(oacc[ct][nt][3]);
      *(ushort4*)(ab + (size_t)k * 256 + c) = pk;
    }
}

extern "C" void kernel_launch(void* const* d_in, const int* in_sizes, int n_in,
                              void* d_out, int out_size, void* d_ws, size_t ws_size,
                              hipStream_t stream) {
  const float* x   = (const float*)d_in[0];
  const float* gns = (const float*)d_in[1];
  const float* gnb = (const float*)d_in[2];
  const float* wq  = (const float*)d_in[3];
  const float* bq  = (const float*)d_in[4];
  const float* wk  = (const float*)d_in[5];
  const float* bk  = (const float*)d_in[6];
  const float* wvp = (const float*)d_in[7];
  const float* bv  = (const float*)d_in[8];
  const float* wo  = (const float*)d_in[9];
  const float* bo  = (const float*)d_in[10];
  float* out = (float*)d_out;

  const int B = 4, C = 256, T = 4096;
  const long long TCe = (long long)T * C;

  char* p = (char*)d_ws;
  unsigned short* hT = (unsigned short*)p; p += (size_t)B * TCe * 2;
  unsigned short* qT = (unsigned short*)p; p += (size_t)B * TCe * 2;
  unsigned short* kT = (unsigned short*)p; p += (size_t)B * TCe * 2;
  unsigned short* vb = (unsigned short*)p; p += (size_t)B * TCe * 2;
  unsigned short* aT = (unsigned short*)p; p += (size_t)B * TCe * 2;
  float* gmean = (float*)p; p += 512;
  float* grstd = (float*)p; p += 512;
  float* pl = (float*)p; p += (size_t)8 * B * T * 4;
  float* ra = (float*)p; p += (size_t)B * T * 4;

  // 1) GroupNorm
  gn_stats_k<<<B * 32, 256, 0, stream>>>(x, gmean, grstd);
  gn_apply_t_k<<<dim3(T / 64, C / 64, B), 256, 0, stream>>>(x, gns, gnb, gmean, grstd, hT);

  // 2) q,k projections (q folded with C^-0.5 = 1/16)
  gemm64_k<true, EPI_WT><<<dim3(T / 64, C / 64, B), 256, 0, stream>>>(
      wq, 0, C, hT, TCe, C, qT, TCe, C, bq, nullptr, 0, 0.0625f, C);
  gemm64_k<true, EPI_WT><<<dim3(T / 64, C / 64, B), 256, 0, stream>>>(
      wk, 0, C, hT, TCe, C, kT, TCe, C, bk, nullptr, 0, 1.0f, C);

  // 3) softmax denominators, then v projection pre-scaled by r (column scale)
  attn_stats3_k<<<dim3(T / 256, 8, B), 256, 0, stream>>>(qT, kT, pl);
  make_r_k<<<B * T / 256, 256, 0, stream>>>(pl, ra);
  gemm64_k<true, EPI_PBR><<<dim3(T / 64, C / 64, B), 256, 0, stream>>>(
      wvp, 0, C, hT, TCe, C, vb, TCe, T, bv, ra, T, 1.0f, C);

  // 4) fused S-recompute + exp + PV (double-buffered P, one barrier/iter)
  attn_pv6h_k<<<256, 512, 0, stream>>>(qT, kT, vb, aT);

  // 5) final projection + bias + residual
  gemm64_k<true, EPI_FIN><<<dim3(T / 64, C / 64, B), 256, 0, stream>>>(
      wo, 0, C, aT, TCe, C, out, TCe, T, bo, x, TCe, 1.0f, C);
}